// Round 1
// baseline (473.728 us; speedup 1.0000x reference)
//
#include <hip/hip_runtime.h>

#define NH 32
#define NKVH 8
#define HD 128
#define GRP 4
#define SCALE 0.08838834764831845f

typedef __attribute__((ext_vector_type(8))) __bf16 bf16x8;
typedef __attribute__((ext_vector_type(4))) float f32x4;
typedef __attribute__((ext_vector_type(8))) unsigned short ushort8;

__device__ inline unsigned short f2bf(float x) {
  unsigned int u = __float_as_uint(x);
  u += 0x7fffu + ((u >> 16) & 1u);   // round-to-nearest-even
  return (unsigned short)(u >> 16);
}

#define KSTR 136   // K LDS row stride (bf16 elems): 128 + 8 pad -> conflict-free b128 reads
#define VSTR 72    // VT LDS row stride: 64 + 8 pad
#define PSTR 72    // P LDS row stride: 64 + 8 pad

// Block: 256 threads = 4 waves. Each block: 64 q-rows of one (kvh, g).
// Wave w owns q-rows q0+16w .. q0+16w+15. Loop over 64-key tiles with
// online softmax; QK^T and PV via mfma_f32_16x16x32_bf16.
__global__ __launch_bounds__(256) void attn_kernel(
    const float* __restrict__ q, const float* __restrict__ k, const float* __restrict__ v,
    const float* __restrict__ kcache, const float* __restrict__ vcache,
    const int* __restrict__ ctx_slots, float* __restrict__ out,
    int seq, int ctx)
{
  __shared__ __align__(16) unsigned short Ks[64 * KSTR];
  __shared__ __align__(16) unsigned short VTs[HD * VSTR];
  __shared__ __align__(16) unsigned short Ps[4 * 16 * PSTR];

  const int bx   = blockIdx.x;
  const int kvh  = bx & 7;          // fastest: blocks sharing K/V land together in dispatch
  const int g    = (bx >> 3) & 3;
  const int qb   = bx >> 5;
  const int q0   = qb * 64;
  const int head = kvh * GRP + g;

  const int tid  = threadIdx.x;
  const int wave = tid >> 6;
  const int lane = tid & 63;
  const int col  = lane & 15;       // MFMA n / C-col index
  const int quad = lane >> 4;

  // ---- Q fragments (A layout: m=lane&15, k=quad*8+j), pre-scaled ----
  bf16x8 qf[4];
  {
    const float* qp = q + (size_t)(q0 + wave*16 + col) * (NH*HD) + head*HD;
    for (int kt = 0; kt < 4; ++kt) {
      const float4 a = *(const float4*)(qp + kt*32 + quad*8);
      const float4 b = *(const float4*)(qp + kt*32 + quad*8 + 4);
      union { ushort8 u; bf16x8 h; } w;
      w.u[0]=f2bf(a.x*SCALE); w.u[1]=f2bf(a.y*SCALE); w.u[2]=f2bf(a.z*SCALE); w.u[3]=f2bf(a.w*SCALE);
      w.u[4]=f2bf(b.x*SCALE); w.u[5]=f2bf(b.y*SCALE); w.u[6]=f2bf(b.z*SCALE); w.u[7]=f2bf(b.w*SCALE);
      qf[kt] = w.h;
    }
  }

  f32x4 accO[8];
  for (int i = 0; i < 8; ++i) accO[i] = (f32x4){0.f,0.f,0.f,0.f};
  float mrow[4] = {-1e30f,-1e30f,-1e30f,-1e30f};
  float lrow[4] = {0.f,0.f,0.f,0.f};

  const int rowbase = q0 + wave*16 + quad*4;  // C-layout row for reg r: rowbase + r
  const int srow = tid >> 2;                  // staging: 4 threads per key-row
  const int sc   = tid & 3;

  const int n_tiles = (ctx + q0 + 64) >> 6;   // keys visible to this block: ctx + q0 + 64

  for (int it = 0; it < n_tiles; ++it) {
    const int kb = it << 6;
    __syncthreads();  // previous iteration's fragment reads done before restage

    // ---- stage K (row-major bf16) and V (transposed bf16) ----
    {
      const int l = kb + srow;
      const float* ksrc; const float* vsrc;
      if (l < ctx) {
        const int slot = ctx_slots[l];
        ksrc = kcache + (size_t)(slot*NKVH + kvh) * HD;
        vsrc = vcache + (size_t)(slot*NKVH + kvh) * HD;
      } else {
        ksrc = k + (size_t)(l - ctx) * (NKVH*HD) + kvh*HD;
        vsrc = v + (size_t)(l - ctx) * (NKVH*HD) + kvh*HD;
      }
      // K: thread covers cols sc*32 .. +31, written as 4x ds_write_b128
      {
        const float4* s4 = (const float4*)ksrc + sc*8;
        unsigned short* kd = &Ks[srow*KSTR + sc*32];
        for (int jj = 0; jj < 4; ++jj) {
          const float4 a = s4[2*jj], b = s4[2*jj+1];
          ushort8 w;
          w[0]=f2bf(a.x); w[1]=f2bf(a.y); w[2]=f2bf(a.z); w[3]=f2bf(a.w);
          w[4]=f2bf(b.x); w[5]=f2bf(b.y); w[6]=f2bf(b.z); w[7]=f2bf(b.w);
          *(ushort8*)(kd + jj*8) = w;
        }
      }
      // V: interleaved col strips -> transposed store VT[d][srow]
      for (int j = 0; j < 8; ++j) {
        const int d0 = sc*4 + j*16;
        const float4 a = *(const float4*)(vsrc + d0);
        VTs[(d0+0)*VSTR + srow] = f2bf(a.x);
        VTs[(d0+1)*VSTR + srow] = f2bf(a.y);
        VTs[(d0+2)*VSTR + srow] = f2bf(a.z);
        VTs[(d0+3)*VSTR + srow] = f2bf(a.w);
      }
    }
    __syncthreads();

    // ---- S = (Q*SCALE) K^T : 4 n-tiles x 4 k-frags ----
    f32x4 S[4];
    for (int nt = 0; nt < 4; ++nt) S[nt] = (f32x4){0.f,0.f,0.f,0.f};
    for (int kt = 0; kt < 4; ++kt)
      for (int nt = 0; nt < 4; ++nt) {
        const bf16x8 kf = *(const bf16x8*)&Ks[(nt*16 + col)*KSTR + kt*32 + quad*8];
        S[nt] = __builtin_amdgcn_mfma_f32_16x16x32_bf16(qf[kt], kf, S[nt], 0, 0, 0);
      }

    // ---- causal mask (wave-uniform guard; no barrier inside) ----
    if (kb + 63 > ctx + q0 + wave*16) {
      for (int r = 0; r < 4; ++r) {
        const int bound = ctx + rowbase + r;
        for (int nt = 0; nt < 4; ++nt) {
          const int l = kb + nt*16 + col;
          if (l > bound) S[nt][r] = -1e30f;
        }
      }
    }

    // ---- online softmax (rows live in C layout: row = quad*4 + r) ----
    float alpha[4];
    for (int r = 0; r < 4; ++r) {
      float mx = fmaxf(fmaxf(S[0][r], S[1][r]), fmaxf(S[2][r], S[3][r]));
      mx = fmaxf(mx, __shfl_xor(mx, 1));
      mx = fmaxf(mx, __shfl_xor(mx, 2));
      mx = fmaxf(mx, __shfl_xor(mx, 4));
      mx = fmaxf(mx, __shfl_xor(mx, 8));
      const float mnew = fmaxf(mrow[r], mx);     // finite after tile 0; -1e30 path -> exp==0
      alpha[r] = __expf(mrow[r] - mnew);
      float rs = 0.f;
      for (int nt = 0; nt < 4; ++nt) {
        const float p = __expf(S[nt][r] - mnew);
        S[nt][r] = p;
        rs += p;
      }
      rs += __shfl_xor(rs, 1);
      rs += __shfl_xor(rs, 2);
      rs += __shfl_xor(rs, 4);
      rs += __shfl_xor(rs, 8);
      lrow[r] = lrow[r]*alpha[r] + rs;
      mrow[r] = mnew;
    }
    for (int d = 0; d < 8; ++d)
      for (int r = 0; r < 4; ++r)
        accO[d][r] *= alpha[r];

    // ---- P: C layout -> LDS -> A layout ----
    unsigned short* pw = &Ps[wave*16*PSTR];
    for (int nt = 0; nt < 4; ++nt)
      for (int r = 0; r < 4; ++r)
        pw[(quad*4 + r)*PSTR + nt*16 + col] = f2bf(S[nt][r]);
    __syncthreads();  // uniform; covers cross-lane P write->read

    bf16x8 pf[2];
    pf[0] = *(const bf16x8*)&pw[col*PSTR + quad*8];
    pf[1] = *(const bf16x8*)&pw[col*PSTR + 32 + quad*8];

    // ---- O += P V : 8 d-tiles x 2 k-frags ----
    for (int nt = 0; nt < 8; ++nt)
      for (int kt = 0; kt < 2; ++kt) {
        const bf16x8 vf = *(const bf16x8*)&VTs[(nt*16 + col)*VSTR + kt*32 + quad*8];
        accO[nt] = __builtin_amdgcn_mfma_f32_16x16x32_bf16(pf[kt], vf, accO[nt], 0, 0, 0);
      }
  }

  // ---- epilogue: O / l ----
  float inv[4];
  for (int r = 0; r < 4; ++r) inv[r] = 1.0f / lrow[r];
  float* op = out + head*HD;
  for (int r = 0; r < 4; ++r) {
    float* orow = op + (size_t)(rowbase + r) * (NH*HD);
    for (int nt = 0; nt < 8; ++nt)
      orow[nt*16 + col] = accO[nt][r] * inv[r];
  }
}

extern "C" void kernel_launch(void* const* d_in, const int* in_sizes, int n_in,
                              void* d_out, int out_size, void* d_ws, size_t ws_size,
                              hipStream_t stream) {
  const float* q  = (const float*)d_in[0];
  const float* k  = (const float*)d_in[1];
  const float* v  = (const float*)d_in[2];
  const float* kc = (const float*)d_in[3];
  const float* vc = (const float*)d_in[4];
  // d_in[5] = slot_mapping: scatter targets are disjoint from context_slots,
  // so the cache update cannot affect the output -> skipped.
  const int* ctx_slots = (const int*)d_in[6];
  float* out = (float*)d_out;

  const int seq = in_sizes[0] / (NH*HD);
  const int ctx = in_sizes[6];
  const int nblocks = (seq / 64) * GRP * NKVH;   // 512
  attn_kernel<<<nblocks, 256, 0, stream>>>(q, k, v, kc, vc, ctx_slots, out, seq, ctx);
}

// Round 2
// 389.363 us; speedup vs baseline: 1.2167x; 1.2167x over previous
//
#include <hip/hip_runtime.h>

#define NH 32
#define NKVH 8
#define HD 128
#define GRP 4
#define SCALE 0.08838834764831845f

typedef __attribute__((ext_vector_type(8))) __bf16 bf16x8;
typedef __attribute__((ext_vector_type(4))) float f32x4;
typedef __attribute__((ext_vector_type(8))) unsigned short ushort8;
typedef __attribute__((ext_vector_type(4))) unsigned short ushort4v;

__device__ inline unsigned short f2bf(float x) {
  unsigned int u = __float_as_uint(x);
  u += 0x7fffu + ((u >> 16) & 1u);   // RNE
  return (unsigned short)(u >> 16);
}

// reduction over the 16 lanes of a DPP row (our 16 S-columns) — pure VALU, no LDS
__device__ inline float dpp_max16(float x) {
  x = fmaxf(x, __int_as_float(__builtin_amdgcn_mov_dpp(__float_as_int(x), 0xB1, 0xF, 0xF, true)));  // quad xor1
  x = fmaxf(x, __int_as_float(__builtin_amdgcn_mov_dpp(__float_as_int(x), 0x4E, 0xF, 0xF, true)));  // quad xor2
  x = fmaxf(x, __int_as_float(__builtin_amdgcn_mov_dpp(__float_as_int(x), 0x141, 0xF, 0xF, true))); // half-mirror
  x = fmaxf(x, __int_as_float(__builtin_amdgcn_mov_dpp(__float_as_int(x), 0x140, 0xF, 0xF, true))); // mirror
  return x;
}
__device__ inline float dpp_sum16(float x) {
  x += __int_as_float(__builtin_amdgcn_mov_dpp(__float_as_int(x), 0xB1, 0xF, 0xF, true));
  x += __int_as_float(__builtin_amdgcn_mov_dpp(__float_as_int(x), 0x4E, 0xF, 0xF, true));
  x += __int_as_float(__builtin_amdgcn_mov_dpp(__float_as_int(x), 0x141, 0xF, 0xF, true));
  x += __int_as_float(__builtin_amdgcn_mov_dpp(__float_as_int(x), 0x140, 0xF, 0xF, true));
  return x;
}

#define KSTR 136   // K row stride (elems): 128+8 pad; +XOR swizzle on 8-elem blocks
#define VSTR 72    // VT row stride: 64+8 pad; +XOR swizzle
#define PSTR 72

__global__ __launch_bounds__(256, 2) void attn_kernel(
    const float* __restrict__ q, const float* __restrict__ k, const float* __restrict__ v,
    const float* __restrict__ kcache, const float* __restrict__ vcache,
    const int* __restrict__ ctx_slots, float* __restrict__ out,
    int seq, int ctx)
{
  __shared__ __align__(16) unsigned short Ks[64 * KSTR];
  __shared__ __align__(16) unsigned short VTs[HD * VSTR];
  __shared__ __align__(16) unsigned short Ps[4 * 16 * PSTR];

  const int bx   = blockIdx.x;
  const int kvh  = bx & 7;
  const int g    = (bx >> 3) & 3;
  const int qb   = bx >> 5;
  const int q0   = qb * 64;
  const int head = kvh * GRP + g;

  const int tid  = threadIdx.x;
  const int wave = tid >> 6;
  const int lane = tid & 63;
  const int col  = lane & 15;
  const int quad = lane >> 4;

  // ---- Q fragments (A layout), pre-scaled ----
  bf16x8 qf[4];
  {
    const float* qp = q + (size_t)(q0 + wave*16 + col) * (NH*HD) + head*HD;
#pragma unroll
    for (int kt = 0; kt < 4; ++kt) {
      const float4 a = *(const float4*)(qp + kt*32 + quad*8);
      const float4 b = *(const float4*)(qp + kt*32 + quad*8 + 4);
      union { ushort8 u; bf16x8 h; } w;
      w.u[0]=f2bf(a.x*SCALE); w.u[1]=f2bf(a.y*SCALE); w.u[2]=f2bf(a.z*SCALE); w.u[3]=f2bf(a.w*SCALE);
      w.u[4]=f2bf(b.x*SCALE); w.u[5]=f2bf(b.y*SCALE); w.u[6]=f2bf(b.z*SCALE); w.u[7]=f2bf(b.w*SCALE);
      qf[kt] = w.h;
    }
  }

  f32x4 accO[8];
#pragma unroll
  for (int i = 0; i < 8; ++i) accO[i] = (f32x4){0.f,0.f,0.f,0.f};
  float mrow[4] = {-1e30f,-1e30f,-1e30f,-1e30f};
  float lrow[4] = {0.f,0.f,0.f,0.f};

  const int rowbase = q0 + wave*16 + quad*4;

  // staging maps
  const int srow = tid >> 2;      // K: row 0..63
  const int sc   = tid & 3;       // K: 32-col strip
  const int dg   = tid & 15;      // V: d-group (8 d)
  const int lg   = tid >> 4;      // V: l-group (4 l)

  const int n_tiles = (ctx + q0 + 64) >> 6;

  float4 kreg[8], vreg[8];

  auto prefetch = [&](int kb) {
    {
      const int l = kb + srow;
      const float* kp;
      if (l < ctx) kp = kcache + ((size_t)ctx_slots[l]*NKVH + kvh)*HD;
      else         kp = k + (size_t)(l - ctx)*(NKVH*HD) + kvh*HD;
      kp += sc*32;
#pragma unroll
      for (int i = 0; i < 8; ++i) kreg[i] = ((const float4*)kp)[i];
    }
#pragma unroll
    for (int i = 0; i < 4; ++i) {
      const int l = kb + lg*4 + i;
      const float* vp;
      if (l < ctx) vp = vcache + ((size_t)ctx_slots[l]*NKVH + kvh)*HD;
      else         vp = v + (size_t)(l - ctx)*(NKVH*HD) + kvh*HD;
      vp += dg*8;
      vreg[2*i]   = ((const float4*)vp)[0];
      vreg[2*i+1] = ((const float4*)vp)[1];
    }
  };

  prefetch(0);

  for (int it = 0; it < n_tiles; ++it) {
    __syncthreads();   // all waves finished reading previous tile's fragments

    // ---- K store: 4x b128, swizzled ----
    {
      const int xs = (srow >> 1) & 7;
      unsigned short* krow = &Ks[srow * KSTR];
#pragma unroll
      for (int jj = 0; jj < 4; ++jj) {
        const int blk = (sc*4 + jj) ^ xs;
        const float4 a = kreg[2*jj], b = kreg[2*jj+1];
        ushort8 w;
        w[0]=f2bf(a.x); w[1]=f2bf(a.y); w[2]=f2bf(a.z); w[3]=f2bf(a.w);
        w[4]=f2bf(b.x); w[5]=f2bf(b.y); w[6]=f2bf(b.z); w[7]=f2bf(b.w);
        *(ushort8*)&krow[blk*8] = w;
      }
    }
    // ---- V store (transposed): 8x b64, swizzled ----
    {
      unsigned short vb[4][8];
#pragma unroll
      for (int i = 0; i < 4; ++i) {
        const float4 a = vreg[2*i], b = vreg[2*i+1];
        vb[i][0]=f2bf(a.x); vb[i][1]=f2bf(a.y); vb[i][2]=f2bf(a.z); vb[i][3]=f2bf(a.w);
        vb[i][4]=f2bf(b.x); vb[i][5]=f2bf(b.y); vb[i][6]=f2bf(b.z); vb[i][7]=f2bf(b.w);
      }
      const int sblk = (lg >> 1) ^ (dg & 7);
      const int loff = sblk*8 + (lg & 1)*4;
#pragma unroll
      for (int j = 0; j < 8; ++j) {
        const int d = dg*8 + j;
        ushort4v w; w[0]=vb[0][j]; w[1]=vb[1][j]; w[2]=vb[2][j]; w[3]=vb[3][j];
        *(ushort4v*)&VTs[d*VSTR + loff] = w;
      }
    }

    if (it + 1 < n_tiles) prefetch((it + 1) << 6);   // overlaps with compute below

    __syncthreads();

    const int kb = it << 6;

    // ---- S = Q K^T ----
    f32x4 S[4];
#pragma unroll
    for (int nt = 0; nt < 4; ++nt) S[nt] = (f32x4){0.f,0.f,0.f,0.f};
#pragma unroll
    for (int kt = 0; kt < 4; ++kt)
#pragma unroll
      for (int nt = 0; nt < 4; ++nt) {
        const int row = nt*16 + col;
        const bf16x8 kf = *(const bf16x8*)&Ks[row*KSTR + (((kt*4+quad) ^ ((row>>1)&7)))*8];
        S[nt] = __builtin_amdgcn_mfma_f32_16x16x32_bf16(qf[kt], kf, S[nt], 0, 0, 0);
      }

    // ---- causal mask ----
    if (kb + 63 > ctx + q0 + wave*16) {
#pragma unroll
      for (int r = 0; r < 4; ++r) {
        const int bound = ctx + rowbase + r;
#pragma unroll
        for (int nt = 0; nt < 4; ++nt) {
          const int l = kb + nt*16 + col;
          if (l > bound) S[nt][r] = -1e30f;
        }
      }
    }

    // ---- online softmax ----
    float alpha[4];
#pragma unroll
    for (int r = 0; r < 4; ++r) {
      float mx = fmaxf(fmaxf(S[0][r], S[1][r]), fmaxf(S[2][r], S[3][r]));
      mx = dpp_max16(mx);
      const float mnew = fmaxf(mrow[r], mx);
      alpha[r] = __expf(mrow[r] - mnew);
      float rs = 0.f;
#pragma unroll
      for (int nt = 0; nt < 4; ++nt) {
        const float p = __expf(S[nt][r] - mnew);
        S[nt][r] = p;
        rs += p;
      }
      rs = dpp_sum16(rs);
      lrow[r] = lrow[r]*alpha[r] + rs;
      mrow[r] = mnew;
    }
#pragma unroll
    for (int d = 0; d < 8; ++d)
#pragma unroll
      for (int r = 0; r < 4; ++r)
        accO[d][r] *= alpha[r];

    // ---- P: C layout -> LDS -> A layout (intra-wave; no barrier) ----
    unsigned short* pw = &Ps[wave*16*PSTR];
#pragma unroll
    for (int nt = 0; nt < 4; ++nt)
#pragma unroll
      for (int r = 0; r < 4; ++r)
        pw[(quad*4 + r)*PSTR + nt*16 + col] = f2bf(S[nt][r]);
    asm volatile("s_waitcnt lgkmcnt(0)" ::: "memory");  // LDS is in-order per wave

    bf16x8 pf[2];
    pf[0] = *(const bf16x8*)&pw[col*PSTR + quad*8];
    pf[1] = *(const bf16x8*)&pw[col*PSTR + 32 + quad*8];

    // ---- O += P V ----
#pragma unroll
    for (int nt = 0; nt < 8; ++nt)
#pragma unroll
      for (int kt = 0; kt < 2; ++kt) {
        const int d = nt*16 + col;
        const bf16x8 vf = *(const bf16x8*)&VTs[d*VSTR + (((kt*4+quad) ^ ((d>>3)&7)))*8];
        accO[nt] = __builtin_amdgcn_mfma_f32_16x16x32_bf16(pf[kt], vf, accO[nt], 0, 0, 0);
      }
  }

  // ---- epilogue ----
  float inv[4];
#pragma unroll
  for (int r = 0; r < 4; ++r) inv[r] = 1.0f / lrow[r];
  float* op = out + head*HD;
#pragma unroll
  for (int r = 0; r < 4; ++r) {
    float* orow = op + (size_t)(rowbase + r) * (NH*HD);
#pragma unroll
    for (int nt = 0; nt < 8; ++nt)
      orow[nt*16 + col] = accO[nt][r] * inv[r];
  }
}

extern "C" void kernel_launch(void* const* d_in, const int* in_sizes, int n_in,
                              void* d_out, int out_size, void* d_ws, size_t ws_size,
                              hipStream_t stream) {
  const float* q  = (const float*)d_in[0];
  const float* k  = (const float*)d_in[1];
  const float* v  = (const float*)d_in[2];
  const float* kc = (const float*)d_in[3];
  const float* vc = (const float*)d_in[4];
  // d_in[5] slot_mapping: targets disjoint from context_slots -> no effect on output
  const int* ctx_slots = (const int*)d_in[6];
  float* out = (float*)d_out;

  const int seq = in_sizes[0] / (NH*HD);
  const int ctx = in_sizes[6];
  const int nblocks = (seq / 64) * GRP * NKVH;   // 512
  attn_kernel<<<nblocks, 256, 0, stream>>>(q, k, v, kc, vc, ctx_slots, out, seq, ctx);
}

// Round 3
// 246.360 us; speedup vs baseline: 1.9229x; 1.5805x over previous
//
#include <hip/hip_runtime.h>

#define NH 32
#define NKVH 8
#define HD 128
#define GRP 4
#define SCALE 0.08838834764831845f

typedef __attribute__((ext_vector_type(8))) __bf16 bf16x8;
typedef __attribute__((ext_vector_type(4))) float f32x4;
typedef __attribute__((ext_vector_type(8))) unsigned short ushort8;

__device__ inline unsigned short f2bf(float x) {
  unsigned int u = __float_as_uint(x);
  u += 0x7fffu + ((u >> 16) & 1u);   // RNE
  return (unsigned short)(u >> 16);
}

__device__ inline float dpp_max16(float x) {
  x = fmaxf(x, __int_as_float(__builtin_amdgcn_mov_dpp(__float_as_int(x), 0xB1, 0xF, 0xF, true)));
  x = fmaxf(x, __int_as_float(__builtin_amdgcn_mov_dpp(__float_as_int(x), 0x4E, 0xF, 0xF, true)));
  x = fmaxf(x, __int_as_float(__builtin_amdgcn_mov_dpp(__float_as_int(x), 0x141, 0xF, 0xF, true)));
  x = fmaxf(x, __int_as_float(__builtin_amdgcn_mov_dpp(__float_as_int(x), 0x140, 0xF, 0xF, true)));
  return x;
}
__device__ inline float dpp_sum16(float x) {
  x += __int_as_float(__builtin_amdgcn_mov_dpp(__float_as_int(x), 0xB1, 0xF, 0xF, true));
  x += __int_as_float(__builtin_amdgcn_mov_dpp(__float_as_int(x), 0x4E, 0xF, 0xF, true));
  x += __int_as_float(__builtin_amdgcn_mov_dpp(__float_as_int(x), 0x141, 0xF, 0xF, true));
  x += __int_as_float(__builtin_amdgcn_mov_dpp(__float_as_int(x), 0x140, 0xF, 0xF, true));
  return x;
}

// global -> LDS direct DMA, 16B/lane. lds base wave-uniform; HW scatters lane*16.
__device__ inline void load_lds16(const unsigned short* g, unsigned short* l) {
  __builtin_amdgcn_global_load_lds((const __attribute__((address_space(1))) unsigned int*)g,
                                   (__attribute__((address_space(3))) unsigned int*)l, 16, 0, 0);
}

#define PSTR 72

// ---------------- pre-pass: build packed bf16 K tiles + transposed V tiles ----------------
// K ws layout: [kvh][tile t][r=l&63][chunk c'=( (d>>3) ^ (r&7) )][e=d&7]   (8192 elems / 16KB per tile)
// V ws layout: [kvh][tile t][d][chunk c'=( ((l&63)>>3) ^ (d&7) )][l&7]     (transposed)
// Both are exactly the LDS image the attention kernel wants, streamed linearly by global_load_lds.
__global__ __launch_bounds__(256) void prepass_kernel(
    const float* __restrict__ k, const float* __restrict__ v,
    const float* __restrict__ kc, const float* __restrict__ vc,
    const int* __restrict__ slots,
    unsigned short* __restrict__ Kws, unsigned short* __restrict__ Vws,
    int ctx, int L, int kblocks)
{
  if (blockIdx.x < (unsigned)kblocks) {
    // K: one thread per (kvh, l, 16-elem d-chunk)
    const int idx = blockIdx.x * 256 + threadIdx.x;
    const int L8  = L * 8;
    const int kvh = idx / L8;
    const int r2  = idx - kvh * L8;
    const int l   = r2 >> 3;
    const int c16 = idx & 7;
    const float* src = (l < ctx)
        ? kc + ((size_t)slots[l] * NKVH + kvh) * HD + c16 * 16
        : k + (size_t)(l - ctx) * (NKVH * HD) + kvh * HD + c16 * 16;
    float4 f[4];
#pragma unroll
    for (int i = 0; i < 4; ++i) f[i] = ((const float4*)src)[i];
    unsigned short* tile = Kws + (size_t)kvh * L * HD + (size_t)(l >> 6) * 8192;
    const int r = l & 63;
    const int c0 = (2 * c16) ^ (r & 7);
    const int c1 = (2 * c16 + 1) ^ (r & 7);
    ushort8 w0, w1;
    w0[0]=f2bf(f[0].x); w0[1]=f2bf(f[0].y); w0[2]=f2bf(f[0].z); w0[3]=f2bf(f[0].w);
    w0[4]=f2bf(f[1].x); w0[5]=f2bf(f[1].y); w0[6]=f2bf(f[1].z); w0[7]=f2bf(f[1].w);
    w1[0]=f2bf(f[2].x); w1[1]=f2bf(f[2].y); w1[2]=f2bf(f[2].z); w1[3]=f2bf(f[2].w);
    w1[4]=f2bf(f[3].x); w1[5]=f2bf(f[3].y); w1[6]=f2bf(f[3].z); w1[7]=f2bf(f[3].w);
    *(ushort8*)&tile[r * 128 + c0 * 8] = w0;
    *(ushort8*)&tile[r * 128 + c1 * 8] = w1;
  } else {
    // V: one thread per (kvh, d, 16-l chunk); lanes = consecutive d -> coalesced reads
    const int idx = (blockIdx.x - kblocks) * 256 + threadIdx.x;
    const int d   = idx & 127;
    const int t2  = idx >> 7;
    const int L16 = L >> 4;
    const int kvh = t2 / L16;
    const int lc  = t2 - kvh * L16;
    const int l0  = lc * 16;
    unsigned short vals[16];
#pragma unroll
    for (int i = 0; i < 16; ++i) {
      const int l = l0 + i;
      const float* sp = (l < ctx)
          ? vc + ((size_t)slots[l] * NKVH + kvh) * HD + d
          : v + (size_t)(l - ctx) * (NKVH * HD) + kvh * HD + d;
      vals[i] = f2bf(*sp);
    }
    unsigned short* tile = Vws + (size_t)kvh * L * HD + (size_t)(l0 >> 6) * 8192;
    const int lt  = l0 & 63;
    const int cl0 = lt >> 3;
    ushort8 w0, w1;
#pragma unroll
    for (int i = 0; i < 8; ++i) { w0[i] = vals[i]; w1[i] = vals[8 + i]; }
    *(ushort8*)&tile[d * 64 + ((cl0 ^ (d & 7)) * 8)] = w0;
    *(ushort8*)&tile[d * 64 + (((cl0 + 1) ^ (d & 7)) * 8)] = w1;
  }
}

// ---------------- main attention kernel ----------------
__global__ __launch_bounds__(256, 2) void attn_kernel(
    const float* __restrict__ q,
    const unsigned short* __restrict__ Kws, const unsigned short* __restrict__ Vws,
    float* __restrict__ out, int ctx, int L)
{
  __shared__ __align__(16) unsigned short Ks[2][8192];
  __shared__ __align__(16) unsigned short VTs[2][8192];
  __shared__ __align__(16) unsigned short Ps[4 * 16 * PSTR];

  const int bx   = blockIdx.x;
  const int kvh  = bx & 7;
  const int g    = (bx >> 3) & 3;
  const int qb   = bx >> 5;
  const int q0   = qb * 64;
  const int head = kvh * GRP + g;

  const int tid  = threadIdx.x;
  const int wave = tid >> 6;
  const int lane = tid & 63;
  const int col  = lane & 15;
  const int quad = lane >> 4;

  // Q fragments (A layout), pre-scaled
  bf16x8 qf[4];
  {
    const float* qp = q + (size_t)(q0 + wave * 16 + col) * (NH * HD) + head * HD;
#pragma unroll
    for (int kt = 0; kt < 4; ++kt) {
      const float4 a = *(const float4*)(qp + kt * 32 + quad * 8);
      const float4 b = *(const float4*)(qp + kt * 32 + quad * 8 + 4);
      union { ushort8 u; bf16x8 h; } w;
      w.u[0]=f2bf(a.x*SCALE); w.u[1]=f2bf(a.y*SCALE); w.u[2]=f2bf(a.z*SCALE); w.u[3]=f2bf(a.w*SCALE);
      w.u[4]=f2bf(b.x*SCALE); w.u[5]=f2bf(b.y*SCALE); w.u[6]=f2bf(b.z*SCALE); w.u[7]=f2bf(b.w*SCALE);
      qf[kt] = w.h;
    }
  }

  f32x4 accO[8];
#pragma unroll
  for (int i = 0; i < 8; ++i) accO[i] = (f32x4){0.f, 0.f, 0.f, 0.f};
  float mrow[4] = {-1e30f, -1e30f, -1e30f, -1e30f};
  float lrow[4] = {0.f, 0.f, 0.f, 0.f};

  const int rowbase = q0 + wave * 16 + quad * 4;
  const size_t kvbase = (size_t)kvh * L * HD;
  const int n_tiles = (ctx + q0 + 64) >> 6;

  // DMA one 16KB K-tile + 16KB V-tile into buffer b. Wave w moves chunks 4w..4w+3 of each.
  auto dma_tile = [&](int t, int b) {
    const unsigned short* kg = Kws + kvbase + (size_t)t * 8192;
    const unsigned short* vg = Vws + kvbase + (size_t)t * 8192;
#pragma unroll
    for (int j = 0; j < 4; ++j) {
      const int ch = wave * 4 + j;                    // 1KB chunk (512 elems)
      load_lds16(kg + ch * 512 + lane * 8, &Ks[b][ch * 512]);
      load_lds16(vg + ch * 512 + lane * 8, &VTs[b][ch * 512]);
    }
  };

  dma_tile(0, 0);

  for (int it = 0; it < n_tiles; ++it) {
    __syncthreads();  // drains this tile's DMA (issued an iteration ago); frees buf^1

    if (it + 1 < n_tiles) dma_tile(it + 1, (it + 1) & 1);  // overlaps compute below

    const unsigned short* Kb = Ks[it & 1];
    const unsigned short* Vb = VTs[it & 1];
    const int kb = it << 6;

    // ---- S = Q K^T ----
    f32x4 S[4];
#pragma unroll
    for (int nt = 0; nt < 4; ++nt) S[nt] = (f32x4){0.f, 0.f, 0.f, 0.f};
#pragma unroll
    for (int kt = 0; kt < 4; ++kt)
#pragma unroll
      for (int nt = 0; nt < 4; ++nt) {
        const int row = nt * 16 + col;
        const bf16x8 kf = *(const bf16x8*)&Kb[row * 128 + (((kt * 4 + quad) ^ (row & 7)) << 3)];
        S[nt] = __builtin_amdgcn_mfma_f32_16x16x32_bf16(qf[kt], kf, S[nt], 0, 0, 0);
      }

    // ---- causal mask ----
    if (kb + 63 > ctx + q0 + wave * 16) {
#pragma unroll
      for (int r = 0; r < 4; ++r) {
        const int bound = ctx + rowbase + r;
#pragma unroll
        for (int nt = 0; nt < 4; ++nt) {
          const int l = kb + nt * 16 + col;
          if (l > bound) S[nt][r] = -1e30f;
        }
      }
    }

    // ---- online softmax ----
    float alpha[4];
#pragma unroll
    for (int r = 0; r < 4; ++r) {
      float mx = fmaxf(fmaxf(S[0][r], S[1][r]), fmaxf(S[2][r], S[3][r]));
      mx = dpp_max16(mx);
      const float mnew = fmaxf(mrow[r], mx);
      alpha[r] = __expf(mrow[r] - mnew);
      float rs = 0.f;
#pragma unroll
      for (int nt = 0; nt < 4; ++nt) {
        const float p = __expf(S[nt][r] - mnew);
        S[nt][r] = p;
        rs += p;
      }
      rs = dpp_sum16(rs);
      lrow[r] = lrow[r] * alpha[r] + rs;
      mrow[r] = mnew;
    }
#pragma unroll
    for (int dd = 0; dd < 8; ++dd)
#pragma unroll
      for (int r = 0; r < 4; ++r)
        accO[dd][r] *= alpha[r];

    // ---- P: C layout -> LDS -> A layout (intra-wave, no barrier) ----
    unsigned short* pw = &Ps[wave * 16 * PSTR];
#pragma unroll
    for (int nt = 0; nt < 4; ++nt)
#pragma unroll
      for (int r = 0; r < 4; ++r)
        pw[(quad * 4 + r) * PSTR + nt * 16 + col] = f2bf(S[nt][r]);
    asm volatile("s_waitcnt lgkmcnt(0)" ::: "memory");

    bf16x8 pf[2];
    pf[0] = *(const bf16x8*)&pw[col * PSTR + quad * 8];
    pf[1] = *(const bf16x8*)&pw[col * PSTR + 32 + quad * 8];

    // ---- O += P V ----
#pragma unroll
    for (int nt = 0; nt < 8; ++nt)
#pragma unroll
      for (int kt = 0; kt < 2; ++kt) {
        const int d = nt * 16 + col;
        const bf16x8 vf = *(const bf16x8*)&Vb[d * 64 + (((kt * 4 + quad) ^ (d & 7)) << 3)];
        accO[nt] = __builtin_amdgcn_mfma_f32_16x16x32_bf16(pf[kt], vf, accO[nt], 0, 0, 0);
      }
  }

  // ---- epilogue ----
  float inv[4];
#pragma unroll
  for (int r = 0; r < 4; ++r) inv[r] = 1.0f / lrow[r];
  float* op = out + head * HD;
#pragma unroll
  for (int r = 0; r < 4; ++r) {
    float* orow = op + (size_t)(rowbase + r) * (NH * HD);
#pragma unroll
    for (int nt = 0; nt < 8; ++nt)
      orow[nt * 16 + col] = accO[nt][r] * inv[r];
  }
}

extern "C" void kernel_launch(void* const* d_in, const int* in_sizes, int n_in,
                              void* d_out, int out_size, void* d_ws, size_t ws_size,
                              hipStream_t stream) {
  const float* q  = (const float*)d_in[0];
  const float* k  = (const float*)d_in[1];
  const float* v  = (const float*)d_in[2];
  const float* kc = (const float*)d_in[3];
  const float* vc = (const float*)d_in[4];
  // d_in[5] slot_mapping: scatter targets disjoint from context_slots -> no output effect
  const int* ctx_slots = (const int*)d_in[6];
  float* out = (float*)d_out;

  const int seq = in_sizes[0] / (NH * HD);
  const int ctx = in_sizes[6];
  const int L   = ctx + seq;                 // 4096

  unsigned short* Kws = (unsigned short*)d_ws;              // NKVH*L*HD bf16 = 8.4MB
  unsigned short* Vws = Kws + (size_t)NKVH * L * HD;        // + 8.4MB (requires ws >= 16.8MB)

  const int kthreads = NKVH * L * (HD / 16);                // 262144
  const int vthreads = NKVH * (L / 16) * HD;                // 262144
  const int kblocks  = kthreads / 256;                      // 1024
  const int vblocks  = vthreads / 256;                      // 1024
  prepass_kernel<<<kblocks + vblocks, 256, 0, stream>>>(k, v, kc, vc, ctx_slots,
                                                        Kws, Vws, ctx, L, kblocks);

  const int nblocks = (seq / 64) * GRP * NKVH;              // 512
  attn_kernel<<<nblocks, 256, 0, stream>>>(q, Kws, Vws, out, ctx, L);
}